// Round 9
// baseline (790.746 us; speedup 1.0000x reference)
//
#include <hip/hip_runtime.h>

typedef short bf16x8 __attribute__((ext_vector_type(8)));
typedef float f32x16 __attribute__((ext_vector_type(16)));

__device__ __forceinline__ unsigned short f2bf(float x) {
    unsigned u = __float_as_uint(x);
    return (unsigned short)((u + 0x7FFFu + ((u >> 16) & 1u)) >> 16);
}
__device__ __forceinline__ float bf2f(unsigned short h) {
    return __uint_as_float(((unsigned)h) << 16);
}
__device__ __forceinline__ unsigned score_key(float s) {
    unsigned u = __float_as_uint(s);
    return (u & 0x80000000u) ? ~u : (u | 0x80000000u);
}
__device__ __forceinline__ void async_cp16(const uint4* g, uint4* l) {
    __builtin_amdgcn_global_load_lds(
        (const __attribute__((address_space(1))) unsigned int*)g,
        (__attribute__((address_space(3))) unsigned int*)l, 16, 0, 0);
}

// truncation split: hi = top-16-bits(x) (exact bf16-trunc), lo = trunc_bf16(x - hi).
// Error: |x - (hi+lo_bf)| <= 2^-16|x| -> far below argmax margin (4-pass absorbs both).
__device__ __forceinline__ void tsplit8(const uint4 a, const uint4 b,
                                        bf16x8& hv, bf16x8& lv) {
    const unsigned X[8] = {a.x, a.y, a.z, a.w, b.x, b.y, b.z, b.w};
    union { unsigned w[4]; bf16x8 v; } H, L;
#pragma unroll
    for (int q = 0; q < 4; ++q) {
        const unsigned u0 = X[2 * q], u1 = X[2 * q + 1];
        const unsigned h0 = u0 & 0xFFFF0000u, h1 = u1 & 0xFFFF0000u;
        H.w[q] = (u0 >> 16) | h1;
        const float l0 = __uint_as_float(u0) - __uint_as_float(h0);
        const float l1 = __uint_as_float(u1) - __uint_as_float(h1);
        L.w[q] = (__float_as_uint(l0) >> 16) | (__float_as_uint(l1) & 0xFFFF0000u);
    }
    hv = H.v; lv = L.v;
}

__global__ void prep_kernel(const float* __restrict__ W2, const float* __restrict__ b2,
                            const float* __restrict__ Ws, const float* __restrict__ bs,
                            float* __restrict__ v, int OUT) {
    int j = threadIdx.x;
    float acc = 0.f;
    for (int o = 0; o < OUT; ++o) acc += W2[j * OUT + o] * Ws[o];
    v[j] = acc;
    if (j == 0) {
        float c = bs[0];
        for (int o = 0; o < OUT; ++o) c += b2[o] * Ws[o];
        v[256] = c;
    }
}

// W1 fragment pack (absmax-0 verified R4-R8): uint4 idx = kt*2048 + (hl*16+nt*2+kc)*64 + lane
// elem j of slot = W1[kt*32 + kc*16 + (lane>>5)*8 + j][nt*32 + (lane&31)]
__global__ void prep_w1frag(const float* __restrict__ W1, uint4* __restrict__ wfrag) {
    const int s = blockIdx.x * 256 + threadIdx.x;
    const int kt = s >> 11;
    const int c = (s >> 6) & 31;
    const int lane = s & 63;
    const int hl = c >> 4;
    const int nt = (c >> 1) & 7;
    const int kc = c & 1;
    const int col = nt * 32 + (lane & 31);
    const int k0 = kt * 32 + kc * 16 + (lane >> 5) * 8;
    unsigned pk[4];
#pragma unroll
    for (int q = 0; q < 4; ++q) {
        float x0 = W1[(size_t)(k0 + 2 * q) * 256 + col];
        float x1 = W1[(size_t)(k0 + 2 * q + 1) * 256 + col];
        unsigned short a0, a1;
        if (hl == 0) { a0 = f2bf(x0); a1 = f2bf(x1); }
        else {
            a0 = f2bf(x0 - bf2f(f2bf(x0)));
            a1 = f2bf(x1 - bf2f(f2bf(x1)));
        }
        pk[q] = (unsigned)a0 | ((unsigned)a1 << 16);
    }
    wfrag[s] = make_uint4(pk[0], pk[1], pk[2], pk[3]);
}

__global__ void init_bins(unsigned long long* __restrict__ bins, int n) {
    int i = blockIdx.x * blockDim.x + threadIdx.x;
    if (i < n) bins[i] = 0ULL;
}

// 256 thr = 4 waves; wave = 128 rows x 64 cols (4 M-subtiles x 2 nt, acc 128 AGPR).
// Register B-reuse 4x across M-subtiles -> 16 B/cyc/wave LDS demand (in budget).
// kt fully unrolled (immediate offsets); kc-staggered A prefetch; uniform vmcnt(16);
// one barrier per kt; B double-buffered via global_load_lds.
__global__ __launch_bounds__(256, 2) void score_kernel(
    const float* __restrict__ desc, const float* __restrict__ kpts,
    const uint4* __restrict__ wfrag,
    const float* __restrict__ b1, const float* __restrict__ g1, const float* __restrict__ be1,
    const int* __restrict__ Hp, const int* __restrict__ Wp,
    const float* __restrict__ v,
    float* __restrict__ scores, unsigned long long* __restrict__ bins,
    int N, int total)
{
    __shared__ uint4 BS[2][2048];        // 64 KB B dbuf
    __shared__ float sumsL[128][8];      // [rowInBlk][cg*2 + {sx,sq}]
    __shared__ float dotL[128][4];       // [rowInBlk][cg]

    const int t = threadIdx.x;
    const int lane = t & 63;
    const int cg = t >> 6;               // wave 0..3 = column group (64 cols each)
    const int c31 = lane & 31;
    const int h = lane >> 5;
    const int R0 = blockIdx.x * 128;

    // A sources: sub s covers rows R0 + s*32 + c31; lane reads 8 floats at h*8 per kc
    const float* asrc[4];
#pragma unroll
    for (int s = 0; s < 4; ++s)
        asrc[s] = desc + (size_t)min(R0 + s * 32 + c31, total - 1) * 256 + h * 8;

    f32x16 acc[4][2];
#pragma unroll
    for (int s = 0; s < 4; ++s)
#pragma unroll
        for (int j = 0; j < 2; ++j) {
            const float bc = b1[cg * 64 + j * 32 + c31];  // fold b1 (col-const per acc)
#pragma unroll
            for (int r = 0; r < 16; ++r) acc[s][j][r] = bc;
        }

    // ---- prologue: stage B[0] (8/thread), A(0) kc0 (8/wave-lane), A(0) kc1 (8)
    uint4 r0[4][2], r1[4][2];            // raw A for current kt: [sub][pair], per kc
    {
#pragma unroll
        for (int j = 0; j < 8; ++j)
            async_cp16(wfrag + j * 256 + t, &BS[0][j * 256 + t]);
#pragma unroll
        for (int s = 0; s < 4; ++s) {
            r0[s][0] = *(const uint4*)(asrc[s] + 0);
            r0[s][1] = *(const uint4*)(asrc[s] + 4);
        }
#pragma unroll
        for (int s = 0; s < 4; ++s) {
            r1[s][0] = *(const uint4*)(asrc[s] + 16);
            r1[s][1] = *(const uint4*)(asrc[s] + 20);
        }
        asm volatile("s_waitcnt vmcnt(16)" ::: "memory");   // stage B[0] landed
        __builtin_amdgcn_s_barrier();
    }

#pragma unroll
    for (int kt = 0; kt < 8; ++kt) {
        const int cur = kt & 1;
        const bool more = (kt < 7);
        // issue stage B[kt+1]
        if (more) {
#pragma unroll
            for (int j = 0; j < 8; ++j)
                async_cp16(wfrag + (size_t)(kt + 1) * 2048 + j * 256 + t,
                           &BS[cur ^ 1][j * 256 + t]);
        }
        // land A(kt) kc0  [keep: Akc1(8) + stage(8) = 16]
        if (more) asm volatile("s_waitcnt vmcnt(16)" ::: "memory");
        else      asm volatile("s_waitcnt vmcnt(8)"  ::: "memory");

#pragma unroll
        for (int kc = 0; kc < 2; ++kc) {
            // convert this kc's raws -> frags (frees raws)
            bf16x8 ah[4], al[4];
#pragma unroll
            for (int s = 0; s < 4; ++s) {
                const uint4 pa = kc ? r1[s][0] : r0[s][0];
                const uint4 pb = kc ? r1[s][1] : r0[s][1];
                tsplit8(pa, pb, ah[s], al[s]);
            }
            // issue A(kt+1) for this kc into the freed raw regs
            if (more) {
                const int off = (kt + 1) * 32 + kc * 16;
#pragma unroll
                for (int s = 0; s < 4; ++s) {
                    if (kc) { r1[s][0] = *(const uint4*)(asrc[s] + off);
                              r1[s][1] = *(const uint4*)(asrc[s] + off + 4); }
                    else    { r0[s][0] = *(const uint4*)(asrc[s] + off);
                              r0[s][1] = *(const uint4*)(asrc[s] + off + 4); }
                }
            }
            // B frags for this cg/kc (4 ds_read_b128, reused by 4 M-subtiles)
            bf16x8 bh[2], bl[2];
#pragma unroll
            for (int j = 0; j < 2; ++j) {
                const int nt = cg * 2 + j;
                bh[j] = *(const bf16x8*)&BS[cur][(nt * 2 + kc) * 64 + lane];
                bl[j] = *(const bf16x8*)&BS[cur][(16 + nt * 2 + kc) * 64 + lane];
            }
            // 32 MFMA, pass-major (same-acc distance 8)
            __builtin_amdgcn_s_setprio(1);
#pragma unroll
            for (int p = 0; p < 4; ++p)
#pragma unroll
                for (int s = 0; s < 4; ++s)
#pragma unroll
                    for (int j = 0; j < 2; ++j) {
                        const bf16x8 pa = (p & 2) ? al[s] : ah[s];
                        const bf16x8 pb = (p & 1) ? bl[j] : bh[j];
                        acc[s][j] = __builtin_amdgcn_mfma_f32_32x32x16_bf16(pa, pb, acc[s][j], 0, 0, 0);
                    }
            __builtin_amdgcn_s_setprio(0);
            // land A(kt) kc1 after kc0 compute  [keep: stage(8) + Akc0'(8) = 16]
            if (kc == 0) {
                if (more) asm volatile("s_waitcnt vmcnt(16)" ::: "memory");
                else      asm volatile("s_waitcnt vmcnt(0)"  ::: "memory");
            }
        }
        // land stage B[kt+1]  [keep: A(kt+1) 16 in flight]; then barrier
        if (more) {
            asm volatile("s_waitcnt vmcnt(16)" ::: "memory");
            __builtin_amdgcn_s_barrier();
        }
    }

    // ---- epilogue: LN cross-cg via LDS, SiLU, score, gid, bin argmax
    float gE[2], beE[2], vE[2];
#pragma unroll
    for (int j = 0; j < 2; ++j) {
        const int c = cg * 64 + j * 32 + c31;
        gE[j] = g1[c]; beE[j] = be1[c]; vE[j] = v[c];
    }
    __syncthreads();
#pragma unroll
    for (int s = 0; s < 4; ++s)
#pragma unroll
        for (int reg = 0; reg < 16; ++reg) {
            float sx = 0.f, sq = 0.f;
#pragma unroll
            for (int j = 0; j < 2; ++j) {
                const float x = acc[s][j][reg];
                sx += x; sq = fmaf(x, x, sq);
            }
#pragma unroll
            for (int m = 1; m <= 16; m <<= 1) {
                sx += __shfl_xor(sx, m);
                sq += __shfl_xor(sq, m);
            }
            if (c31 == 0) {
                const int rowL = s * 32 + (reg & 3) + 8 * (reg >> 2) + 4 * h;
                sumsL[rowL][cg * 2 + 0] = sx;
                sumsL[rowL][cg * 2 + 1] = sq;
            }
        }
    __syncthreads();
#pragma unroll
    for (int s = 0; s < 4; ++s)
#pragma unroll
        for (int reg = 0; reg < 16; ++reg) {
            const int rowL = s * 32 + (reg & 3) + 8 * (reg >> 2) + 4 * h;
            const float4 sa = *(const float4*)&sumsL[rowL][0];
            const float4 sb = *(const float4*)&sumsL[rowL][4];
            const float mu = (sa.x + sa.z + sb.x + sb.z) * (1.f / 256.f);
            const float var = (sa.y + sa.w + sb.y + sb.w) * (1.f / 256.f) - mu * mu;
            const float rs = 1.f / sqrtf(var + 1e-5f);
            float dot = 0.f;
#pragma unroll
            for (int j = 0; j < 2; ++j) {
                const float hv = (acc[s][j][reg] - mu) * rs * gE[j] + beE[j];
                const float sg = 1.f / (1.f + __expf(-hv));
                dot = fmaf(vE[j], hv * sg, dot);
            }
#pragma unroll
            for (int m = 1; m <= 16; m <<= 1) dot += __shfl_xor(dot, m);
            if (c31 == 0) dotL[rowL][cg] = dot;
        }
    __syncthreads();
    if (t < 128) {
        const int row = R0 + t;
        if (row < total) {
            const float4 d4 = *(const float4*)&dotL[t][0];
            const float sc = d4.x + d4.y + d4.z + d4.w + v[256];
            scores[row] = sc;
            const float Wf = (float)Wp[0];
            const int Hi = Hp[0];
            const float t02 = (float)(0.2 * (double)Hi);
            const float t05 = (float)(0.5 * (double)Hi);
            const float t03 = (float)(0.3 * (double)Hi);
            const float x = kpts[(size_t)row * 2 + 0];
            const float y = kpts[(size_t)row * 2 + 1];
            int g = -1;
            if (y > t05) {
                int bgx = (int)(x / Wf * 16.f); bgx = min(max(bgx, 0), 15);
                int bgy = (int)((y - t05) / t05 * 6.f); bgy = min(max(bgy, 0), 5);
                g = 32 + bgy * 16 + bgx;
            } else if (y > t02) {
                int mgx = (int)(x / Wf * 8.f); mgx = min(max(mgx, 0), 7);
                int mgy = (int)((y - t02) / t03 * 4.f); mgy = min(max(mgy, 0), 3);
                g = mgy * 8 + mgx;
            }
            if (g >= 0) {
                const int bb = row / N;
                const int n = row - bb * N;
                const unsigned long long pk =
                    ((unsigned long long)score_key(sc) << 32) | (unsigned)(~(unsigned)n);
                atomicMax(&bins[bb * 128 + g], pk);
            }
        }
    }
}

__global__ __launch_bounds__(256) void finalize_kernel(
    const float* __restrict__ scores, const unsigned long long* __restrict__ bins,
    const float* __restrict__ desc, const float* __restrict__ kpts,
    const int* __restrict__ tkp, float* __restrict__ out, int B, int N)
{
    const int b = blockIdx.x, t = threadIdx.x;
    const int topk = tkp[0];
    __shared__ int selL[512];
    __shared__ int nselS;
    __shared__ unsigned long long red[256];
    __shared__ unsigned long long binL[128];

    if (t < 128) binL[t] = bins[b * 128 + t];
    __syncthreads();
    if (t == 0) {
        int c = 0;
        for (int i = 0; i < 128; ++i)
            if ((binL[i] >> 32) != 0ULL) selL[c++] = (int)(~(unsigned)binL[i]);
        nselS = c;
    }
    __syncthreads();
    const int nsel = nselS;

    for (int need = nsel; need < topk; ++need) {
        unsigned long long best = 0ULL;
        for (int i = t; i < N; i += 256) {
            bool taken = false;
            for (int s2 = 0; s2 < need; ++s2)
                if (selL[s2] == i) { taken = true; break; }
            if (!taken) {
                const unsigned long long pk =
                    ((unsigned long long)score_key(scores[(size_t)b * N + i]) << 32)
                    | (unsigned)(~(unsigned)i);
                if (pk > best) best = pk;
            }
        }
        red[t] = best;
        __syncthreads();
        for (int off = 128; off > 0; off >>= 1) {
            if (t < off) { if (red[t + off] > red[t]) red[t] = red[t + off]; }
            __syncthreads();
        }
        if (t == 0) selL[need] = (int)(~(unsigned)red[0]);
        __syncthreads();
    }

    float* o_feat = out;
    float* o_kpts = out + (size_t)B * topk * 256;
    float* o_idx  = out + (size_t)B * topk * 258;
    for (int e = t; e < topk * 64; e += 256) {
        const int j = e >> 6, q4 = e & 63;
        const int n = selL[j];
        *(float4*)&o_feat[((size_t)b * topk + j) * 256 + q4 * 4] =
            *(const float4*)&desc[((size_t)b * N + n) * 256 + q4 * 4];
    }
    for (int j = t; j < topk; j += 256) {
        const int n = selL[j];
        o_kpts[((size_t)b * topk + j) * 2 + 0] = kpts[((size_t)b * N + n) * 2 + 0];
        o_kpts[((size_t)b * topk + j) * 2 + 1] = kpts[((size_t)b * N + n) * 2 + 1];
        o_idx[(size_t)b * topk + j] = (float)n;
    }
}

extern "C" void kernel_launch(void* const* d_in, const int* in_sizes, int n_in,
                              void* d_out, int out_size, void* d_ws, size_t ws_size,
                              hipStream_t stream) {
    const float* kpts = (const float*)d_in[0];
    const float* desc = (const float*)d_in[1];
    const int*   Hp   = (const int*)d_in[2];
    const int*   Wp   = (const int*)d_in[3];
    const int*   tkp  = (const int*)d_in[4];
    const float* W1   = (const float*)d_in[5];
    const float* b1   = (const float*)d_in[6];
    const float* g1   = (const float*)d_in[7];
    const float* be1  = (const float*)d_in[8];
    const float* W2   = (const float*)d_in[9];
    const float* b2   = (const float*)d_in[10];
    const float* Ws   = (const float*)d_in[11];
    const float* bs   = (const float*)d_in[12];

    const int total = in_sizes[1] / 256;   // B*N
    const int BT    = out_size / 259;      // B*topk
    const int B     = BT / 128;
    const int N     = total / B;
    const int OUT   = in_sizes[11];

    float* ws_v      = (float*)d_ws;
    float* ws_scores = ws_v + 512;
    size_t off = ((size_t)(512 + total) * 4 + 255) & ~(size_t)255;
    unsigned long long* ws_bins = (unsigned long long*)((char*)d_ws + off);
    size_t off2 = (off + (size_t)B * 128 * 8 + 255) & ~(size_t)255;
    uint4* ws_wfrag = (uint4*)((char*)d_ws + off2);        // 256 KB

    prep_kernel<<<1, 256, 0, stream>>>(W2, b2, Ws, bs, ws_v, OUT);
    prep_w1frag<<<64, 256, 0, stream>>>(W1, ws_wfrag);
    init_bins<<<(B * 128 + 255) / 256, 256, 0, stream>>>(ws_bins, B * 128);
    score_kernel<<<(total + 127) / 128, 256, 0, stream>>>(
        desc, kpts, ws_wfrag, b1, g1, be1, Hp, Wp, ws_v, ws_scores, ws_bins, N, total);
    finalize_kernel<<<B, 256, 0, stream>>>(ws_scores, ws_bins, desc, kpts, tkp,
                                           (float*)d_out, B, N);
}

// Round 10
// 785.588 us; speedup vs baseline: 1.0066x; 1.0066x over previous
//
#include <hip/hip_runtime.h>

typedef short bf16x8 __attribute__((ext_vector_type(8)));
typedef float f32x16 __attribute__((ext_vector_type(16)));

__device__ __forceinline__ unsigned short f2bf(float x) {
    unsigned u = __float_as_uint(x);
    return (unsigned short)((u + 0x7FFFu + ((u >> 16) & 1u)) >> 16);
}
__device__ __forceinline__ float bf2f(unsigned short h) {
    return __uint_as_float(((unsigned)h) << 16);
}
__device__ __forceinline__ unsigned score_key(float s) {
    unsigned u = __float_as_uint(s);
    return (u & 0x80000000u) ? ~u : (u | 0x80000000u);
}
__device__ __forceinline__ void async_cp16(const uint4* g, uint4* l) {
    __builtin_amdgcn_global_load_lds(
        (const __attribute__((address_space(1))) unsigned int*)g,
        (__attribute__((address_space(3))) unsigned int*)l, 16, 0, 0);
}

// truncation split: hi = top-16-bits(x) (exact bf16-trunc), lo = trunc_bf16(x - hi).
// Error: |x - (hi+lo_bf)| <= 2^-16|x| -> far below argmax margin (4-pass absorbs both).
__device__ __forceinline__ void tsplit8(const uint4 a, const uint4 b,
                                        bf16x8& hv, bf16x8& lv) {
    const unsigned X[8] = {a.x, a.y, a.z, a.w, b.x, b.y, b.z, b.w};
    union { unsigned w[4]; bf16x8 v; } H, L;
#pragma unroll
    for (int q = 0; q < 4; ++q) {
        const unsigned u0 = X[2 * q], u1 = X[2 * q + 1];
        const unsigned h0 = u0 & 0xFFFF0000u, h1 = u1 & 0xFFFF0000u;
        H.w[q] = (u0 >> 16) | h1;
        const float l0 = __uint_as_float(u0) - __uint_as_float(h0);
        const float l1 = __uint_as_float(u1) - __uint_as_float(h1);
        L.w[q] = (__float_as_uint(l0) >> 16) | (__float_as_uint(l1) & 0xFFFF0000u);
    }
    hv = H.v; lv = L.v;
}

__global__ void prep_kernel(const float* __restrict__ W2, const float* __restrict__ b2,
                            const float* __restrict__ Ws, const float* __restrict__ bs,
                            float* __restrict__ v, int OUT) {
    int j = threadIdx.x;
    float acc = 0.f;
    for (int o = 0; o < OUT; ++o) acc += W2[j * OUT + o] * Ws[o];
    v[j] = acc;
    if (j == 0) {
        float c = bs[0];
        for (int o = 0; o < OUT; ++o) c += b2[o] * Ws[o];
        v[256] = c;
    }
}

// W1 fragment pack (absmax-0 verified R4-R8): uint4 idx = kt*2048 + (hl*16+nt*2+kc)*64 + lane
// elem j of slot = W1[kt*32 + kc*16 + (lane>>5)*8 + j][nt*32 + (lane&31)]
__global__ void prep_w1frag(const float* __restrict__ W1, uint4* __restrict__ wfrag) {
    const int s = blockIdx.x * 256 + threadIdx.x;
    const int kt = s >> 11;
    const int c = (s >> 6) & 31;
    const int lane = s & 63;
    const int hl = c >> 4;
    const int nt = (c >> 1) & 7;
    const int kc = c & 1;
    const int col = nt * 32 + (lane & 31);
    const int k0 = kt * 32 + kc * 16 + (lane >> 5) * 8;
    unsigned pk[4];
#pragma unroll
    for (int q = 0; q < 4; ++q) {
        float x0 = W1[(size_t)(k0 + 2 * q) * 256 + col];
        float x1 = W1[(size_t)(k0 + 2 * q + 1) * 256 + col];
        unsigned short a0, a1;
        if (hl == 0) { a0 = f2bf(x0); a1 = f2bf(x1); }
        else {
            a0 = f2bf(x0 - bf2f(f2bf(x0)));
            a1 = f2bf(x1 - bf2f(f2bf(x1)));
        }
        pk[q] = (unsigned)a0 | ((unsigned)a1 << 16);
    }
    wfrag[s] = make_uint4(pk[0], pk[1], pk[2], pk[3]);
}

__global__ void init_bins(unsigned long long* __restrict__ bins, int n) {
    int i = blockIdx.x * blockDim.x + threadIdx.x;
    if (i < n) bins[i] = 0ULL;
}

// 256 thr = 4 waves; wave = 128 rows x 64 cols (4 M-subtiles x 2 nt, acc 128 AGPR).
// Register B-reuse 4x across M-subtiles -> 16 B/cyc/wave LDS demand (in budget).
// kt fully unrolled (immediate offsets); kc-staggered A prefetch; uniform vmcnt(16);
// one barrier per kt; B double-buffered via global_load_lds.
__global__ __launch_bounds__(256, 2) void score_kernel(
    const float* __restrict__ desc, const float* __restrict__ kpts,
    const uint4* __restrict__ wfrag,
    const float* __restrict__ b1, const float* __restrict__ g1, const float* __restrict__ be1,
    const int* __restrict__ Hp, const int* __restrict__ Wp,
    const float* __restrict__ v,
    float* __restrict__ scores, unsigned long long* __restrict__ bins,
    int N, int total)
{
    __shared__ uint4 BS[2][2048];        // 64 KB B dbuf
    __shared__ float sumsL[128][8];      // [rowInBlk][cg*2 + {sx,sq}]
    __shared__ float dotL[128][4];       // [rowInBlk][cg]

    const int t = threadIdx.x;
    const int lane = t & 63;
    const int cg = t >> 6;               // wave 0..3 = column group (64 cols each)
    const int c31 = lane & 31;
    const int h = lane >> 5;
    const int R0 = blockIdx.x * 128;

    // A sources: sub s covers rows R0 + s*32 + c31; lane reads 8 floats at h*8 per kc
    const float* asrc[4];
#pragma unroll
    for (int s = 0; s < 4; ++s)
        asrc[s] = desc + (size_t)min(R0 + s * 32 + c31, total - 1) * 256 + h * 8;

    f32x16 acc[4][2];
#pragma unroll
    for (int s = 0; s < 4; ++s)
#pragma unroll
        for (int j = 0; j < 2; ++j) {
            const float bc = b1[cg * 64 + j * 32 + c31];  // fold b1 (col-const per acc)
#pragma unroll
            for (int r = 0; r < 16; ++r) acc[s][j][r] = bc;
        }

    // ---- prologue: stage B[0] (8/thread), A(0) kc0 (8/wave-lane), A(0) kc1 (8)
    uint4 r0[4][2], r1[4][2];            // raw A for current kt: [sub][pair], per kc
    {
#pragma unroll
        for (int j = 0; j < 8; ++j)
            async_cp16(wfrag + j * 256 + t, &BS[0][j * 256 + t]);
#pragma unroll
        for (int s = 0; s < 4; ++s) {
            r0[s][0] = *(const uint4*)(asrc[s] + 0);
            r0[s][1] = *(const uint4*)(asrc[s] + 4);
        }
#pragma unroll
        for (int s = 0; s < 4; ++s) {
            r1[s][0] = *(const uint4*)(asrc[s] + 16);
            r1[s][1] = *(const uint4*)(asrc[s] + 20);
        }
        asm volatile("s_waitcnt vmcnt(16)" ::: "memory");   // stage B[0] landed
        __builtin_amdgcn_s_barrier();
    }

#pragma unroll
    for (int kt = 0; kt < 8; ++kt) {
        const int cur = kt & 1;
        const bool more = (kt < 7);
        // issue stage B[kt+1]
        if (more) {
#pragma unroll
            for (int j = 0; j < 8; ++j)
                async_cp16(wfrag + (size_t)(kt + 1) * 2048 + j * 256 + t,
                           &BS[cur ^ 1][j * 256 + t]);
        }
        // land A(kt) kc0  [keep: Akc1(8) + stage(8) = 16]
        if (more) asm volatile("s_waitcnt vmcnt(16)" ::: "memory");
        else      asm volatile("s_waitcnt vmcnt(8)"  ::: "memory");

#pragma unroll
        for (int kc = 0; kc < 2; ++kc) {
            // convert this kc's raws -> frags (frees raws)
            bf16x8 ah[4], al[4];
#pragma unroll
            for (int s = 0; s < 4; ++s) {
                const uint4 pa = kc ? r1[s][0] : r0[s][0];
                const uint4 pb = kc ? r1[s][1] : r0[s][1];
                tsplit8(pa, pb, ah[s], al[s]);
            }
            // issue A(kt+1) for this kc into the freed raw regs
            if (more) {
                const int off = (kt + 1) * 32 + kc * 16;
#pragma unroll
                for (int s = 0; s < 4; ++s) {
                    if (kc) { r1[s][0] = *(const uint4*)(asrc[s] + off);
                              r1[s][1] = *(const uint4*)(asrc[s] + off + 4); }
                    else    { r0[s][0] = *(const uint4*)(asrc[s] + off);
                              r0[s][1] = *(const uint4*)(asrc[s] + off + 4); }
                }
            }
            // B frags for this cg/kc (4 ds_read_b128, reused by 4 M-subtiles)
            bf16x8 bh[2], bl[2];
#pragma unroll
            for (int j = 0; j < 2; ++j) {
                const int nt = cg * 2 + j;
                bh[j] = *(const bf16x8*)&BS[cur][(nt * 2 + kc) * 64 + lane];
                bl[j] = *(const bf16x8*)&BS[cur][(16 + nt * 2 + kc) * 64 + lane];
            }
            // 32 MFMA, pass-major (same-acc distance 8)
            __builtin_amdgcn_s_setprio(1);
#pragma unroll
            for (int p = 0; p < 4; ++p)
#pragma unroll
                for (int s = 0; s < 4; ++s)
#pragma unroll
                    for (int j = 0; j < 2; ++j) {
                        const bf16x8 pa = (p & 2) ? al[s] : ah[s];
                        const bf16x8 pb = (p & 1) ? bl[j] : bh[j];
                        acc[s][j] = __builtin_amdgcn_mfma_f32_32x32x16_bf16(pa, pb, acc[s][j], 0, 0, 0);
                    }
            __builtin_amdgcn_s_setprio(0);
            // land A(kt) kc1 after kc0 compute  [keep: stage(8) + Akc0'(8) = 16]
            if (kc == 0) {
                if (more) asm volatile("s_waitcnt vmcnt(16)" ::: "memory");
                else      asm volatile("s_waitcnt vmcnt(0)"  ::: "memory");
            }
        }
        // land stage B[kt+1]  [keep: A(kt+1) 16 in flight]; then barrier
        if (more) {
            asm volatile("s_waitcnt vmcnt(16)" ::: "memory");
            __builtin_amdgcn_s_barrier();
        }
    }

    // ---- epilogue: LN cross-cg via LDS, SiLU, score, gid, bin argmax
    float gE[2], beE[2], vE[2];
#pragma unroll
    for (int j = 0; j < 2; ++j) {
        const int c = cg * 64 + j * 32 + c31;
        gE[j] = g1[c]; beE[j] = be1[c]; vE[j] = v[c];
    }
    __syncthreads();
#pragma unroll
    for (int s = 0; s < 4; ++s)
#pragma unroll
        for (int reg = 0; reg < 16; ++reg) {
            float sx = 0.f, sq = 0.f;
#pragma unroll
            for (int j = 0; j < 2; ++j) {
                const float x = acc[s][j][reg];
                sx += x; sq = fmaf(x, x, sq);
            }
#pragma unroll
            for (int m = 1; m <= 16; m <<= 1) {
                sx += __shfl_xor(sx, m);
                sq += __shfl_xor(sq, m);
            }
            if (c31 == 0) {
                const int rowL = s * 32 + (reg & 3) + 8 * (reg >> 2) + 4 * h;
                sumsL[rowL][cg * 2 + 0] = sx;
                sumsL[rowL][cg * 2 + 1] = sq;
            }
        }
    __syncthreads();
#pragma unroll
    for (int s = 0; s < 4; ++s)
#pragma unroll
        for (int reg = 0; reg < 16; ++reg) {
            const int rowL = s * 32 + (reg & 3) + 8 * (reg >> 2) + 4 * h;
            const float4 sa = *(const float4*)&sumsL[rowL][0];
            const float4 sb = *(const float4*)&sumsL[rowL][4];
            const float mu = (sa.x + sa.z + sb.x + sb.z) * (1.f / 256.f);
            const float var = (sa.y + sa.w + sb.y + sb.w) * (1.f / 256.f) - mu * mu;
            const float rs = 1.f / sqrtf(var + 1e-5f);
            float dot = 0.f;
#pragma unroll
            for (int j = 0; j < 2; ++j) {
                const float hv = (acc[s][j][reg] - mu) * rs * gE[j] + beE[j];
                const float sg = 1.f / (1.f + __expf(-hv));
                dot = fmaf(vE[j], hv * sg, dot);
            }
#pragma unroll
            for (int m = 1; m <= 16; m <<= 1) dot += __shfl_xor(dot, m);
            if (c31 == 0) dotL[rowL][cg] = dot;
        }
    __syncthreads();
    if (t < 128) {
        const int row = R0 + t;
        if (row < total) {
            const float4 d4 = *(const float4*)&dotL[t][0];
            const float sc = d4.x + d4.y + d4.z + d4.w + v[256];
            scores[row] = sc;
            const float Wf = (float)Wp[0];
            const int Hi = Hp[0];
            const float t02 = (float)(0.2 * (double)Hi);
            const float t05 = (float)(0.5 * (double)Hi);
            const float t03 = (float)(0.3 * (double)Hi);
            const float x = kpts[(size_t)row * 2 + 0];
            const float y = kpts[(size_t)row * 2 + 1];
            int g = -1;
            if (y > t05) {
                int bgx = (int)(x / Wf * 16.f); bgx = min(max(bgx, 0), 15);
                int bgy = (int)((y - t05) / t05 * 6.f); bgy = min(max(bgy, 0), 5);
                g = 32 + bgy * 16 + bgx;
            } else if (y > t02) {
                int mgx = (int)(x / Wf * 8.f); mgx = min(max(mgx, 0), 7);
                int mgy = (int)((y - t02) / t03 * 4.f); mgy = min(max(mgy, 0), 3);
                g = mgy * 8 + mgx;
            }
            if (g >= 0) {
                const int bb = row / N;
                const int n = row - bb * N;
                const unsigned long long pk =
                    ((unsigned long long)score_key(sc) << 32) | (unsigned)(~(unsigned)n);
                atomicMax(&bins[bb * 128 + g], pk);
            }
        }
    }
}

__global__ __launch_bounds__(256) void finalize_kernel(
    const float* __restrict__ scores, const unsigned long long* __restrict__ bins,
    const float* __restrict__ desc, const float* __restrict__ kpts,
    const int* __restrict__ tkp, float* __restrict__ out, int B, int N)
{
    const int b = blockIdx.x, t = threadIdx.x;
    const int topk = tkp[0];
    __shared__ int selL[512];
    __shared__ int nselS;
    __shared__ unsigned long long red[256];
    __shared__ unsigned long long binL[128];

    if (t < 128) binL[t] = bins[b * 128 + t];
    __syncthreads();
    if (t == 0) {
        int c = 0;
        for (int i = 0; i < 128; ++i)
            if ((binL[i] >> 32) != 0ULL) selL[c++] = (int)(~(unsigned)binL[i]);
        nselS = c;
    }
    __syncthreads();
    const int nsel = nselS;

    for (int need = nsel; need < topk; ++need) {
        unsigned long long best = 0ULL;
        for (int i = t; i < N; i += 256) {
            bool taken = false;
            for (int s2 = 0; s2 < need; ++s2)
                if (selL[s2] == i) { taken = true; break; }
            if (!taken) {
                const unsigned long long pk =
                    ((unsigned long long)score_key(scores[(size_t)b * N + i]) << 32)
                    | (unsigned)(~(unsigned)i);
                if (pk > best) best = pk;
            }
        }
        red[t] = best;
        __syncthreads();
        for (int off = 128; off > 0; off >>= 1) {
            if (t < off) { if (red[t + off] > red[t]) red[t] = red[t + off]; }
            __syncthreads();
        }
        if (t == 0) selL[need] = (int)(~(unsigned)red[0]);
        __syncthreads();
    }

    float* o_feat = out;
    float* o_kpts = out + (size_t)B * topk * 256;
    float* o_idx  = out + (size_t)B * topk * 258;
    for (int e = t; e < topk * 64; e += 256) {
        const int j = e >> 6, q4 = e & 63;
        const int n = selL[j];
        *(float4*)&o_feat[((size_t)b * topk + j) * 256 + q4 * 4] =
            *(const float4*)&desc[((size_t)b * N + n) * 256 + q4 * 4];
    }
    for (int j = t; j < topk; j += 256) {
        const int n = selL[j];
        o_kpts[((size_t)b * topk + j) * 2 + 0] = kpts[((size_t)b * N + n) * 2 + 0];
        o_kpts[((size_t)b * topk + j) * 2 + 1] = kpts[((size_t)b * N + n) * 2 + 1];
        o_idx[(size_t)b * topk + j] = (float)n;
    }
}

extern "C" void kernel_launch(void* const* d_in, const int* in_sizes, int n_in,
                              void* d_out, int out_size, void* d_ws, size_t ws_size,
                              hipStream_t stream) {
    const float* kpts = (const float*)d_in[0];
    const float* desc = (const float*)d_in[1];
    const int*   Hp   = (const int*)d_in[2];
    const int*   Wp   = (const int*)d_in[3];
    const int*   tkp  = (const int*)d_in[4];
    const float* W1   = (const float*)d_in[5];
    const float* b1   = (const float*)d_in[6];
    const float* g1   = (const float*)d_in[7];
    const float* be1  = (const float*)d_in[8];
    const float* W2   = (const float*)d_in[9];
    const float* b2   = (const float*)d_in[10];
    const float* Ws   = (const float*)d_in[11];
    const float* bs   = (const float*)d_in[12];

    const int total = in_sizes[1] / 256;   // B*N
    const int BT    = out_size / 259;      // B*topk
    const int B     = BT / 128;
    const int N     = total / B;
    const int OUT   = in_sizes[11];

    float* ws_v      = (float*)d_ws;
    float* ws_scores = ws_v + 512;
    size_t off = ((size_t)(512 + total) * 4 + 255) & ~(size_t)255;
    unsigned long long* ws_bins = (unsigned long long*)((char*)d_ws + off);
    size_t off2 = (off + (size_t)B * 128 * 8 + 255) & ~(size_t)255;
    uint4* ws_wfrag = (uint4*)((char*)d_ws + off2);        // 256 KB

    prep_kernel<<<1, 256, 0, stream>>>(W2, b2, Ws, bs, ws_v, OUT);
    prep_w1frag<<<64, 256, 0, stream>>>(W1, ws_wfrag);
    init_bins<<<(B * 128 + 255) / 256, 256, 0, stream>>>(ws_bins, B * 128);
    score_kernel<<<(total + 127) / 128, 256, 0, stream>>>(
        desc, kpts, ws_wfrag, b1, g1, be1, Hp, Wp, ws_v, ws_scores, ws_bins, N, total);
    finalize_kernel<<<B, 256, 0, stream>>>(ws_scores, ws_bins, desc, kpts, tkp,
                                           (float*)d_out, B, N);
}

// Round 11
// 784.861 us; speedup vs baseline: 1.0075x; 1.0009x over previous
//
#include <hip/hip_runtime.h>

typedef short bf16x8 __attribute__((ext_vector_type(8)));
typedef float f32x16 __attribute__((ext_vector_type(16)));

__device__ __forceinline__ unsigned short f2bf(float x) {
    unsigned u = __float_as_uint(x);
    return (unsigned short)((u + 0x7FFFu + ((u >> 16) & 1u)) >> 16);
}
__device__ __forceinline__ float bf2f(unsigned short h) {
    return __uint_as_float(((unsigned)h) << 16);
}
__device__ __forceinline__ unsigned score_key(float s) {
    unsigned u = __float_as_uint(s);
    return (u & 0x80000000u) ? ~u : (u | 0x80000000u);
}
__device__ __forceinline__ void async_cp16(const uint4* g, uint4* l) {
    __builtin_amdgcn_global_load_lds(
        (const __attribute__((address_space(1))) unsigned int*)g,
        (__attribute__((address_space(3))) unsigned int*)l, 16, 0, 0);
}

// truncation split: hi = top-16-bits(x) (exact bf16-trunc), lo = trunc_bf16(x - hi).
// Error: |x - (hi+lo_bf)| <= 2^-16|x| -> far below argmax margin (4-pass absorbs both).
__device__ __forceinline__ void tsplit8(const uint4 a, const uint4 b,
                                        bf16x8& hv, bf16x8& lv) {
    const unsigned X[8] = {a.x, a.y, a.z, a.w, b.x, b.y, b.z, b.w};
    union { unsigned w[4]; bf16x8 v; } H, L;
#pragma unroll
    for (int q = 0; q < 4; ++q) {
        const unsigned u0 = X[2 * q], u1 = X[2 * q + 1];
        const unsigned h0 = u0 & 0xFFFF0000u, h1 = u1 & 0xFFFF0000u;
        H.w[q] = (u0 >> 16) | h1;
        const float l0 = __uint_as_float(u0) - __uint_as_float(h0);
        const float l1 = __uint_as_float(u1) - __uint_as_float(h1);
        L.w[q] = (__float_as_uint(l0) >> 16) | (__float_as_uint(l1) & 0xFFFF0000u);
    }
    hv = H.v; lv = L.v;
}

__global__ void prep_kernel(const float* __restrict__ W2, const float* __restrict__ b2,
                            const float* __restrict__ Ws, const float* __restrict__ bs,
                            float* __restrict__ v, int OUT) {
    int j = threadIdx.x;
    float acc = 0.f;
    for (int o = 0; o < OUT; ++o) acc += W2[j * OUT + o] * Ws[o];
    v[j] = acc;
    if (j == 0) {
        float c = bs[0];
        for (int o = 0; o < OUT; ++o) c += b2[o] * Ws[o];
        v[256] = c;
    }
}

// W1 fragment pack (absmax-0 verified R4-R8): uint4 idx = kt*2048 + (hl*16+nt*2+kc)*64 + lane
// elem j of slot = W1[kt*32 + kc*16 + (lane>>5)*8 + j][nt*32 + (lane&31)]
__global__ void prep_w1frag(const float* __restrict__ W1, uint4* __restrict__ wfrag) {
    const int s = blockIdx.x * 256 + threadIdx.x;
    const int kt = s >> 11;
    const int c = (s >> 6) & 31;
    const int lane = s & 63;
    const int hl = c >> 4;
    const int nt = (c >> 1) & 7;
    const int kc = c & 1;
    const int col = nt * 32 + (lane & 31);
    const int k0 = kt * 32 + kc * 16 + (lane >> 5) * 8;
    unsigned pk[4];
#pragma unroll
    for (int q = 0; q < 4; ++q) {
        float x0 = W1[(size_t)(k0 + 2 * q) * 256 + col];
        float x1 = W1[(size_t)(k0 + 2 * q + 1) * 256 + col];
        unsigned short a0, a1;
        if (hl == 0) { a0 = f2bf(x0); a1 = f2bf(x1); }
        else {
            a0 = f2bf(x0 - bf2f(f2bf(x0)));
            a1 = f2bf(x1 - bf2f(f2bf(x1)));
        }
        pk[q] = (unsigned)a0 | ((unsigned)a1 << 16);
    }
    wfrag[s] = make_uint4(pk[0], pk[1], pk[2], pk[3]);
}

__global__ void init_bins(unsigned long long* __restrict__ bins, int n) {
    int i = blockIdx.x * blockDim.x + threadIdx.x;
    if (i < n) bins[i] = 0ULL;
}

// 256 thr = 4 waves; wave = 128 rows x 64 cols (4 M-subtiles x 2 nt, acc 128 AGPR).
// Register B-reuse 4x across M-subtiles -> 16 B/cyc/wave LDS demand (in budget).
// kt fully unrolled (immediate offsets); kc-staggered A prefetch; uniform vmcnt(16);
// one barrier per kt; B double-buffered via global_load_lds.
__global__ __launch_bounds__(256, 2) void score_kernel(
    const float* __restrict__ desc, const float* __restrict__ kpts,
    const uint4* __restrict__ wfrag,
    const float* __restrict__ b1, const float* __restrict__ g1, const float* __restrict__ be1,
    const int* __restrict__ Hp, const int* __restrict__ Wp,
    const float* __restrict__ v,
    float* __restrict__ scores, unsigned long long* __restrict__ bins,
    int N, int total)
{
    __shared__ uint4 BS[2][2048];        // 64 KB B dbuf
    __shared__ float sumsL[128][8];      // [rowInBlk][cg*2 + {sx,sq}]
    __shared__ float dotL[128][4];       // [rowInBlk][cg]

    const int t = threadIdx.x;
    const int lane = t & 63;
    const int cg = t >> 6;               // wave 0..3 = column group (64 cols each)
    const int c31 = lane & 31;
    const int h = lane >> 5;
    const int R0 = blockIdx.x * 128;

    // A sources: sub s covers rows R0 + s*32 + c31; lane reads 8 floats at h*8 per kc
    const float* asrc[4];
#pragma unroll
    for (int s = 0; s < 4; ++s)
        asrc[s] = desc + (size_t)min(R0 + s * 32 + c31, total - 1) * 256 + h * 8;

    f32x16 acc[4][2];
#pragma unroll
    for (int s = 0; s < 4; ++s)
#pragma unroll
        for (int j = 0; j < 2; ++j) {
            const float bc = b1[cg * 64 + j * 32 + c31];  // fold b1 (col-const per acc)
#pragma unroll
            for (int r = 0; r < 16; ++r) acc[s][j][r] = bc;
        }

    // ---- prologue: stage B[0] (8/thread), A(0) kc0 (8/wave-lane), A(0) kc1 (8)
    uint4 r0[4][2], r1[4][2];            // raw A for current kt: [sub][pair], per kc
    {
#pragma unroll
        for (int j = 0; j < 8; ++j)
            async_cp16(wfrag + j * 256 + t, &BS[0][j * 256 + t]);
#pragma unroll
        for (int s = 0; s < 4; ++s) {
            r0[s][0] = *(const uint4*)(asrc[s] + 0);
            r0[s][1] = *(const uint4*)(asrc[s] + 4);
        }
#pragma unroll
        for (int s = 0; s < 4; ++s) {
            r1[s][0] = *(const uint4*)(asrc[s] + 16);
            r1[s][1] = *(const uint4*)(asrc[s] + 20);
        }
        asm volatile("s_waitcnt vmcnt(16)" ::: "memory");   // stage B[0] landed
        __builtin_amdgcn_s_barrier();
    }

#pragma unroll
    for (int kt = 0; kt < 8; ++kt) {
        const int cur = kt & 1;
        const bool more = (kt < 7);
        // issue stage B[kt+1]
        if (more) {
#pragma unroll
            for (int j = 0; j < 8; ++j)
                async_cp16(wfrag + (size_t)(kt + 1) * 2048 + j * 256 + t,
                           &BS[cur ^ 1][j * 256 + t]);
        }
        // land A(kt) kc0  [keep: Akc1(8) + stage(8) = 16]
        if (more) asm volatile("s_waitcnt vmcnt(16)" ::: "memory");
        else      asm volatile("s_waitcnt vmcnt(8)"  ::: "memory");

#pragma unroll
        for (int kc = 0; kc < 2; ++kc) {
            // convert this kc's raws -> frags (frees raws)
            bf16x8 ah[4], al[4];
#pragma unroll
            for (int s = 0; s < 4; ++s) {
                const uint4 pa = kc ? r1[s][0] : r0[s][0];
                const uint4 pb = kc ? r1[s][1] : r0[s][1];
                tsplit8(pa, pb, ah[s], al[s]);
            }
            // issue A(kt+1) for this kc into the freed raw regs
            if (more) {
                const int off = (kt + 1) * 32 + kc * 16;
#pragma unroll
                for (int s = 0; s < 4; ++s) {
                    if (kc) { r1[s][0] = *(const uint4*)(asrc[s] + off);
                              r1[s][1] = *(const uint4*)(asrc[s] + off + 4); }
                    else    { r0[s][0] = *(const uint4*)(asrc[s] + off);
                              r0[s][1] = *(const uint4*)(asrc[s] + off + 4); }
                }
            }
            // B frags for this cg/kc (4 ds_read_b128, reused by 4 M-subtiles)
            bf16x8 bh[2], bl[2];
#pragma unroll
            for (int j = 0; j < 2; ++j) {
                const int nt = cg * 2 + j;
                bh[j] = *(const bf16x8*)&BS[cur][(nt * 2 + kc) * 64 + lane];
                bl[j] = *(const bf16x8*)&BS[cur][(16 + nt * 2 + kc) * 64 + lane];
            }
            // 32 MFMA, pass-major (same-acc distance 8)
            __builtin_amdgcn_s_setprio(1);
#pragma unroll
            for (int p = 0; p < 4; ++p)
#pragma unroll
                for (int s = 0; s < 4; ++s)
#pragma unroll
                    for (int j = 0; j < 2; ++j) {
                        const bf16x8 pa = (p & 2) ? al[s] : ah[s];
                        const bf16x8 pb = (p & 1) ? bl[j] : bh[j];
                        acc[s][j] = __builtin_amdgcn_mfma_f32_32x32x16_bf16(pa, pb, acc[s][j], 0, 0, 0);
                    }
            __builtin_amdgcn_s_setprio(0);
            // land A(kt) kc1 after kc0 compute  [keep: stage(8) + Akc0'(8) = 16]
            if (kc == 0) {
                if (more) asm volatile("s_waitcnt vmcnt(16)" ::: "memory");
                else      asm volatile("s_waitcnt vmcnt(0)"  ::: "memory");
            }
        }
        // land stage B[kt+1]  [keep: A(kt+1) 16 in flight]; then barrier
        if (more) {
            asm volatile("s_waitcnt vmcnt(16)" ::: "memory");
            __builtin_amdgcn_s_barrier();
        }
    }

    // ---- epilogue: LN cross-cg via LDS, SiLU, score, gid, bin argmax
    float gE[2], beE[2], vE[2];
#pragma unroll
    for (int j = 0; j < 2; ++j) {
        const int c = cg * 64 + j * 32 + c31;
        gE[j] = g1[c]; beE[j] = be1[c]; vE[j] = v[c];
    }
    __syncthreads();
#pragma unroll
    for (int s = 0; s < 4; ++s)
#pragma unroll
        for (int reg = 0; reg < 16; ++reg) {
            float sx = 0.f, sq = 0.f;
#pragma unroll
            for (int j = 0; j < 2; ++j) {
                const float x = acc[s][j][reg];
                sx += x; sq = fmaf(x, x, sq);
            }
#pragma unroll
            for (int m = 1; m <= 16; m <<= 1) {
                sx += __shfl_xor(sx, m);
                sq += __shfl_xor(sq, m);
            }
            if (c31 == 0) {
                const int rowL = s * 32 + (reg & 3) + 8 * (reg >> 2) + 4 * h;
                sumsL[rowL][cg * 2 + 0] = sx;
                sumsL[rowL][cg * 2 + 1] = sq;
            }
        }
    __syncthreads();
#pragma unroll
    for (int s = 0; s < 4; ++s)
#pragma unroll
        for (int reg = 0; reg < 16; ++reg) {
            const int rowL = s * 32 + (reg & 3) + 8 * (reg >> 2) + 4 * h;
            const float4 sa = *(const float4*)&sumsL[rowL][0];
            const float4 sb = *(const float4*)&sumsL[rowL][4];
            const float mu = (sa.x + sa.z + sb.x + sb.z) * (1.f / 256.f);
            const float var = (sa.y + sa.w + sb.y + sb.w) * (1.f / 256.f) - mu * mu;
            const float rs = 1.f / sqrtf(var + 1e-5f);
            float dot = 0.f;
#pragma unroll
            for (int j = 0; j < 2; ++j) {
                const float hv = (acc[s][j][reg] - mu) * rs * gE[j] + beE[j];
                const float sg = 1.f / (1.f + __expf(-hv));
                dot = fmaf(vE[j], hv * sg, dot);
            }
#pragma unroll
            for (int m = 1; m <= 16; m <<= 1) dot += __shfl_xor(dot, m);
            if (c31 == 0) dotL[rowL][cg] = dot;
        }
    __syncthreads();
    if (t < 128) {
        const int row = R0 + t;
        if (row < total) {
            const float4 d4 = *(const float4*)&dotL[t][0];
            const float sc = d4.x + d4.y + d4.z + d4.w + v[256];
            scores[row] = sc;
            const float Wf = (float)Wp[0];
            const int Hi = Hp[0];
            const float t02 = (float)(0.2 * (double)Hi);
            const float t05 = (float)(0.5 * (double)Hi);
            const float t03 = (float)(0.3 * (double)Hi);
            const float x = kpts[(size_t)row * 2 + 0];
            const float y = kpts[(size_t)row * 2 + 1];
            int g = -1;
            if (y > t05) {
                int bgx = (int)(x / Wf * 16.f); bgx = min(max(bgx, 0), 15);
                int bgy = (int)((y - t05) / t05 * 6.f); bgy = min(max(bgy, 0), 5);
                g = 32 + bgy * 16 + bgx;
            } else if (y > t02) {
                int mgx = (int)(x / Wf * 8.f); mgx = min(max(mgx, 0), 7);
                int mgy = (int)((y - t02) / t03 * 4.f); mgy = min(max(mgy, 0), 3);
                g = mgy * 8 + mgx;
            }
            if (g >= 0) {
                const int bb = row / N;
                const int n = row - bb * N;
                const unsigned long long pk =
                    ((unsigned long long)score_key(sc) << 32) | (unsigned)(~(unsigned)n);
                atomicMax(&bins[bb * 128 + g], pk);
            }
        }
    }
}

__global__ __launch_bounds__(256) void finalize_kernel(
    const float* __restrict__ scores, const unsigned long long* __restrict__ bins,
    const float* __restrict__ desc, const float* __restrict__ kpts,
    const int* __restrict__ tkp, float* __restrict__ out, int B, int N)
{
    const int b = blockIdx.x, t = threadIdx.x;
    const int topk = tkp[0];
    __shared__ int selL[512];
    __shared__ int nselS;
    __shared__ unsigned long long red[256];
    __shared__ unsigned long long binL[128];

    if (t < 128) binL[t] = bins[b * 128 + t];
    __syncthreads();
    if (t == 0) {
        int c = 0;
        for (int i = 0; i < 128; ++i)
            if ((binL[i] >> 32) != 0ULL) selL[c++] = (int)(~(unsigned)binL[i]);
        nselS = c;
    }
    __syncthreads();
    const int nsel = nselS;

    for (int need = nsel; need < topk; ++need) {
        unsigned long long best = 0ULL;
        for (int i = t; i < N; i += 256) {
            bool taken = false;
            for (int s2 = 0; s2 < need; ++s2)
                if (selL[s2] == i) { taken = true; break; }
            if (!taken) {
                const unsigned long long pk =
                    ((unsigned long long)score_key(scores[(size_t)b * N + i]) << 32)
                    | (unsigned)(~(unsigned)i);
                if (pk > best) best = pk;
            }
        }
        red[t] = best;
        __syncthreads();
        for (int off = 128; off > 0; off >>= 1) {
            if (t < off) { if (red[t + off] > red[t]) red[t] = red[t + off]; }
            __syncthreads();
        }
        if (t == 0) selL[need] = (int)(~(unsigned)red[0]);
        __syncthreads();
    }

    float* o_feat = out;
    float* o_kpts = out + (size_t)B * topk * 256;
    float* o_idx  = out + (size_t)B * topk * 258;
    for (int e = t; e < topk * 64; e += 256) {
        const int j = e >> 6, q4 = e & 63;
        const int n = selL[j];
        *(float4*)&o_feat[((size_t)b * topk + j) * 256 + q4 * 4] =
            *(const float4*)&desc[((size_t)b * N + n) * 256 + q4 * 4];
    }
    for (int j = t; j < topk; j += 256) {
        const int n = selL[j];
        o_kpts[((size_t)b * topk + j) * 2 + 0] = kpts[((size_t)b * N + n) * 2 + 0];
        o_kpts[((size_t)b * topk + j) * 2 + 1] = kpts[((size_t)b * N + n) * 2 + 1];
        o_idx[(size_t)b * topk + j] = (float)n;
    }
}

extern "C" void kernel_launch(void* const* d_in, const int* in_sizes, int n_in,
                              void* d_out, int out_size, void* d_ws, size_t ws_size,
                              hipStream_t stream) {
    const float* kpts = (const float*)d_in[0];
    const float* desc = (const float*)d_in[1];
    const int*   Hp   = (const int*)d_in[2];
    const int*   Wp   = (const int*)d_in[3];
    const int*   tkp  = (const int*)d_in[4];
    const float* W1   = (const float*)d_in[5];
    const float* b1   = (const float*)d_in[6];
    const float* g1   = (const float*)d_in[7];
    const float* be1  = (const float*)d_in[8];
    const float* W2   = (const float*)d_in[9];
    const float* b2   = (const float*)d_in[10];
    const float* Ws   = (const float*)d_in[11];
    const float* bs   = (const float*)d_in[12];

    const int total = in_sizes[1] / 256;   // B*N
    const int BT    = out_size / 259;      // B*topk
    const int B     = BT / 128;
    const int N     = total / B;
    const int OUT   = in_sizes[11];

    float* ws_v      = (float*)d_ws;
    float* ws_scores = ws_v + 512;
    size_t off = ((size_t)(512 + total) * 4 + 255) & ~(size_t)255;
    unsigned long long* ws_bins = (unsigned long long*)((char*)d_ws + off);
    size_t off2 = (off + (size_t)B * 128 * 8 + 255) & ~(size_t)255;
    uint4* ws_wfrag = (uint4*)((char*)d_ws + off2);        // 256 KB

    prep_kernel<<<1, 256, 0, stream>>>(W2, b2, Ws, bs, ws_v, OUT);
    prep_w1frag<<<64, 256, 0, stream>>>(W1, ws_wfrag);
    init_bins<<<(B * 128 + 255) / 256, 256, 0, stream>>>(ws_bins, B * 128);
    score_kernel<<<(total + 127) / 128, 256, 0, stream>>>(
        desc, kpts, ws_wfrag, b1, g1, be1, Hp, Wp, ws_v, ws_scores, ws_bins, N, total);
    finalize_kernel<<<B, 256, 0, stream>>>(ws_scores, ws_bins, desc, kpts, tkp,
                                           (float*)d_out, B, N);
}

// Round 12
// 781.854 us; speedup vs baseline: 1.0114x; 1.0038x over previous
//
#include <hip/hip_runtime.h>

typedef short bf16x8 __attribute__((ext_vector_type(8)));
typedef float f32x16 __attribute__((ext_vector_type(16)));

__device__ __forceinline__ unsigned short f2bf(float x) {
    unsigned u = __float_as_uint(x);
    return (unsigned short)((u + 0x7FFFu + ((u >> 16) & 1u)) >> 16);
}
__device__ __forceinline__ float bf2f(unsigned short h) {
    return __uint_as_float(((unsigned)h) << 16);
}
__device__ __forceinline__ unsigned score_key(float s) {
    unsigned u = __float_as_uint(s);
    return (u & 0x80000000u) ? ~u : (u | 0x80000000u);
}
__device__ __forceinline__ void async_cp16(const uint4* g, uint4* l) {
    __builtin_amdgcn_global_load_lds(
        (const __attribute__((address_space(1))) unsigned int*)g,
        (__attribute__((address_space(3))) unsigned int*)l, 16, 0, 0);
}

// truncation split: hi = top-16-bits(x) (exact bf16-trunc), lo = trunc_bf16(x - hi).
// Error: |x - (hi+lo_bf)| <= 2^-16|x| -> far below argmax margin (4-pass absorbs both).
__device__ __forceinline__ void tsplit8(const uint4 a, const uint4 b,
                                        bf16x8& hv, bf16x8& lv) {
    const unsigned X[8] = {a.x, a.y, a.z, a.w, b.x, b.y, b.z, b.w};
    union { unsigned w[4]; bf16x8 v; } H, L;
#pragma unroll
    for (int q = 0; q < 4; ++q) {
        const unsigned u0 = X[2 * q], u1 = X[2 * q + 1];
        const unsigned h0 = u0 & 0xFFFF0000u, h1 = u1 & 0xFFFF0000u;
        H.w[q] = (u0 >> 16) | h1;
        const float l0 = __uint_as_float(u0) - __uint_as_float(h0);
        const float l1 = __uint_as_float(u1) - __uint_as_float(h1);
        L.w[q] = (__float_as_uint(l0) >> 16) | (__float_as_uint(l1) & 0xFFFF0000u);
    }
    hv = H.v; lv = L.v;
}

__global__ void prep_kernel(const float* __restrict__ W2, const float* __restrict__ b2,
                            const float* __restrict__ Ws, const float* __restrict__ bs,
                            float* __restrict__ v, int OUT) {
    int j = threadIdx.x;
    float acc = 0.f;
    for (int o = 0; o < OUT; ++o) acc += W2[j * OUT + o] * Ws[o];
    v[j] = acc;
    if (j == 0) {
        float c = bs[0];
        for (int o = 0; o < OUT; ++o) c += b2[o] * Ws[o];
        v[256] = c;
    }
}

// W1 fragment pack (absmax-0 verified R4-R8): uint4 idx = kt*2048 + (hl*16+nt*2+kc)*64 + lane
// elem j of slot = W1[kt*32 + kc*16 + (lane>>5)*8 + j][nt*32 + (lane&31)]
__global__ void prep_w1frag(const float* __restrict__ W1, uint4* __restrict__ wfrag) {
    const int s = blockIdx.x * 256 + threadIdx.x;
    const int kt = s >> 11;
    const int c = (s >> 6) & 31;
    const int lane = s & 63;
    const int hl = c >> 4;
    const int nt = (c >> 1) & 7;
    const int kc = c & 1;
    const int col = nt * 32 + (lane & 31);
    const int k0 = kt * 32 + kc * 16 + (lane >> 5) * 8;
    unsigned pk[4];
#pragma unroll
    for (int q = 0; q < 4; ++q) {
        float x0 = W1[(size_t)(k0 + 2 * q) * 256 + col];
        float x1 = W1[(size_t)(k0 + 2 * q + 1) * 256 + col];
        unsigned short a0, a1;
        if (hl == 0) { a0 = f2bf(x0); a1 = f2bf(x1); }
        else {
            a0 = f2bf(x0 - bf2f(f2bf(x0)));
            a1 = f2bf(x1 - bf2f(f2bf(x1)));
        }
        pk[q] = (unsigned)a0 | ((unsigned)a1 << 16);
    }
    wfrag[s] = make_uint4(pk[0], pk[1], pk[2], pk[3]);
}

__global__ void init_bins(unsigned long long* __restrict__ bins, int n) {
    int i = blockIdx.x * blockDim.x + threadIdx.x;
    if (i < n) bins[i] = 0ULL;
}

// 256 thr = 4 waves; wave = 128 rows x 64 cols (4 M-subtiles x 2 nt, acc 128 AGPR).
// Register B-reuse 4x across M-subtiles -> 16 B/cyc/wave LDS demand (in budget).
// kt fully unrolled (immediate offsets); kc-staggered A prefetch; uniform vmcnt(16);
// one barrier per kt; B double-buffered via global_load_lds.
__global__ __launch_bounds__(256, 2) void score_kernel(
    const float* __restrict__ desc, const float* __restrict__ kpts,
    const uint4* __restrict__ wfrag,
    const float* __restrict__ b1, const float* __restrict__ g1, const float* __restrict__ be1,
    const int* __restrict__ Hp, const int* __restrict__ Wp,
    const float* __restrict__ v,
    float* __restrict__ scores, unsigned long long* __restrict__ bins,
    int N, int total)
{
    __shared__ uint4 BS[2][2048];        // 64 KB B dbuf
    __shared__ float sumsL[128][8];      // [rowInBlk][cg*2 + {sx,sq}]
    __shared__ float dotL[128][4];       // [rowInBlk][cg]

    const int t = threadIdx.x;
    const int lane = t & 63;
    const int cg = t >> 6;               // wave 0..3 = column group (64 cols each)
    const int c31 = lane & 31;
    const int h = lane >> 5;
    const int R0 = blockIdx.x * 128;

    // A sources: sub s covers rows R0 + s*32 + c31; lane reads 8 floats at h*8 per kc
    const float* asrc[4];
#pragma unroll
    for (int s = 0; s < 4; ++s)
        asrc[s] = desc + (size_t)min(R0 + s * 32 + c31, total - 1) * 256 + h * 8;

    f32x16 acc[4][2];
#pragma unroll
    for (int s = 0; s < 4; ++s)
#pragma unroll
        for (int j = 0; j < 2; ++j) {
            const float bc = b1[cg * 64 + j * 32 + c31];  // fold b1 (col-const per acc)
#pragma unroll
            for (int r = 0; r < 16; ++r) acc[s][j][r] = bc;
        }

    // ---- prologue: stage B[0] (8/thread), A(0) kc0 (8/wave-lane), A(0) kc1 (8)
    uint4 r0[4][2], r1[4][2];            // raw A for current kt: [sub][pair], per kc
    {
#pragma unroll
        for (int j = 0; j < 8; ++j)
            async_cp16(wfrag + j * 256 + t, &BS[0][j * 256 + t]);
#pragma unroll
        for (int s = 0; s < 4; ++s) {
            r0[s][0] = *(const uint4*)(asrc[s] + 0);
            r0[s][1] = *(const uint4*)(asrc[s] + 4);
        }
#pragma unroll
        for (int s = 0; s < 4; ++s) {
            r1[s][0] = *(const uint4*)(asrc[s] + 16);
            r1[s][1] = *(const uint4*)(asrc[s] + 20);
        }
        asm volatile("s_waitcnt vmcnt(16)" ::: "memory");   // stage B[0] landed
        __builtin_amdgcn_s_barrier();
    }

#pragma unroll
    for (int kt = 0; kt < 8; ++kt) {
        const int cur = kt & 1;
        const bool more = (kt < 7);
        // issue stage B[kt+1]
        if (more) {
#pragma unroll
            for (int j = 0; j < 8; ++j)
                async_cp16(wfrag + (size_t)(kt + 1) * 2048 + j * 256 + t,
                           &BS[cur ^ 1][j * 256 + t]);
        }
        // land A(kt) kc0  [keep: Akc1(8) + stage(8) = 16]
        if (more) asm volatile("s_waitcnt vmcnt(16)" ::: "memory");
        else      asm volatile("s_waitcnt vmcnt(8)"  ::: "memory");

#pragma unroll
        for (int kc = 0; kc < 2; ++kc) {
            // convert this kc's raws -> frags (frees raws)
            bf16x8 ah[4], al[4];
#pragma unroll
            for (int s = 0; s < 4; ++s) {
                const uint4 pa = kc ? r1[s][0] : r0[s][0];
                const uint4 pb = kc ? r1[s][1] : r0[s][1];
                tsplit8(pa, pb, ah[s], al[s]);
            }
            // issue A(kt+1) for this kc into the freed raw regs
            if (more) {
                const int off = (kt + 1) * 32 + kc * 16;
#pragma unroll
                for (int s = 0; s < 4; ++s) {
                    if (kc) { r1[s][0] = *(const uint4*)(asrc[s] + off);
                              r1[s][1] = *(const uint4*)(asrc[s] + off + 4); }
                    else    { r0[s][0] = *(const uint4*)(asrc[s] + off);
                              r0[s][1] = *(const uint4*)(asrc[s] + off + 4); }
                }
            }
            // B frags for this cg/kc (4 ds_read_b128, reused by 4 M-subtiles)
            bf16x8 bh[2], bl[2];
#pragma unroll
            for (int j = 0; j < 2; ++j) {
                const int nt = cg * 2 + j;
                bh[j] = *(const bf16x8*)&BS[cur][(nt * 2 + kc) * 64 + lane];
                bl[j] = *(const bf16x8*)&BS[cur][(16 + nt * 2 + kc) * 64 + lane];
            }
            // 32 MFMA, pass-major (same-acc distance 8)
            __builtin_amdgcn_s_setprio(1);
#pragma unroll
            for (int p = 0; p < 4; ++p)
#pragma unroll
                for (int s = 0; s < 4; ++s)
#pragma unroll
                    for (int j = 0; j < 2; ++j) {
                        const bf16x8 pa = (p & 2) ? al[s] : ah[s];
                        const bf16x8 pb = (p & 1) ? bl[j] : bh[j];
                        acc[s][j] = __builtin_amdgcn_mfma_f32_32x32x16_bf16(pa, pb, acc[s][j], 0, 0, 0);
                    }
            __builtin_amdgcn_s_setprio(0);
            // land A(kt) kc1 after kc0 compute  [keep: stage(8) + Akc0'(8) = 16]
            if (kc == 0) {
                if (more) asm volatile("s_waitcnt vmcnt(16)" ::: "memory");
                else      asm volatile("s_waitcnt vmcnt(0)"  ::: "memory");
            }
        }
        // land stage B[kt+1]  [keep: A(kt+1) 16 in flight]; then barrier
        if (more) {
            asm volatile("s_waitcnt vmcnt(16)" ::: "memory");
            __builtin_amdgcn_s_barrier();
        }
    }

    // ---- epilogue: LN cross-cg via LDS, SiLU, score, gid, bin argmax
    float gE[2], beE[2], vE[2];
#pragma unroll
    for (int j = 0; j < 2; ++j) {
        const int c = cg * 64 + j * 32 + c31;
        gE[j] = g1[c]; beE[j] = be1[c]; vE[j] = v[c];
    }
    __syncthreads();
#pragma unroll
    for (int s = 0; s < 4; ++s)
#pragma unroll
        for (int reg = 0; reg < 16; ++reg) {
            float sx = 0.f, sq = 0.f;
#pragma unroll
            for (int j = 0; j < 2; ++j) {
                const float x = acc[s][j][reg];
                sx += x; sq = fmaf(x, x, sq);
            }
#pragma unroll
            for (int m = 1; m <= 16; m <<= 1) {
                sx += __shfl_xor(sx, m);
                sq += __shfl_xor(sq, m);
            }
            if (c31 == 0) {
                const int rowL = s * 32 + (reg & 3) + 8 * (reg >> 2) + 4 * h;
                sumsL[rowL][cg * 2 + 0] = sx;
                sumsL[rowL][cg * 2 + 1] = sq;
            }
        }
    __syncthreads();
#pragma unroll
    for (int s = 0; s < 4; ++s)
#pragma unroll
        for (int reg = 0; reg < 16; ++reg) {
            const int rowL = s * 32 + (reg & 3) + 8 * (reg >> 2) + 4 * h;
            const float4 sa = *(const float4*)&sumsL[rowL][0];
            const float4 sb = *(const float4*)&sumsL[rowL][4];
            const float mu = (sa.x + sa.z + sb.x + sb.z) * (1.f / 256.f);
            const float var = (sa.y + sa.w + sb.y + sb.w) * (1.f / 256.f) - mu * mu;
            const float rs = 1.f / sqrtf(var + 1e-5f);
            float dot = 0.f;
#pragma unroll
            for (int j = 0; j < 2; ++j) {
                const float hv = (acc[s][j][reg] - mu) * rs * gE[j] + beE[j];
                const float sg = 1.f / (1.f + __expf(-hv));
                dot = fmaf(vE[j], hv * sg, dot);
            }
#pragma unroll
            for (int m = 1; m <= 16; m <<= 1) dot += __shfl_xor(dot, m);
            if (c31 == 0) dotL[rowL][cg] = dot;
        }
    __syncthreads();
    if (t < 128) {
        const int row = R0 + t;
        if (row < total) {
            const float4 d4 = *(const float4*)&dotL[t][0];
            const float sc = d4.x + d4.y + d4.z + d4.w + v[256];
            scores[row] = sc;
            const float Wf = (float)Wp[0];
            const int Hi = Hp[0];
            const float t02 = (float)(0.2 * (double)Hi);
            const float t05 = (float)(0.5 * (double)Hi);
            const float t03 = (float)(0.3 * (double)Hi);
            const float x = kpts[(size_t)row * 2 + 0];
            const float y = kpts[(size_t)row * 2 + 1];
            int g = -1;
            if (y > t05) {
                int bgx = (int)(x / Wf * 16.f); bgx = min(max(bgx, 0), 15);
                int bgy = (int)((y - t05) / t05 * 6.f); bgy = min(max(bgy, 0), 5);
                g = 32 + bgy * 16 + bgx;
            } else if (y > t02) {
                int mgx = (int)(x / Wf * 8.f); mgx = min(max(mgx, 0), 7);
                int mgy = (int)((y - t02) / t03 * 4.f); mgy = min(max(mgy, 0), 3);
                g = mgy * 8 + mgx;
            }
            if (g >= 0) {
                const int bb = row / N;
                const int n = row - bb * N;
                const unsigned long long pk =
                    ((unsigned long long)score_key(sc) << 32) | (unsigned)(~(unsigned)n);
                atomicMax(&bins[bb * 128 + g], pk);
            }
        }
    }
}

__global__ __launch_bounds__(256) void finalize_kernel(
    const float* __restrict__ scores, const unsigned long long* __restrict__ bins,
    const float* __restrict__ desc, const float* __restrict__ kpts,
    const int* __restrict__ tkp, float* __restrict__ out, int B, int N)
{
    const int b = blockIdx.x, t = threadIdx.x;
    const int topk = tkp[0];
    __shared__ int selL[512];
    __shared__ int nselS;
    __shared__ unsigned long long red[256];
    __shared__ unsigned long long binL[128];

    if (t < 128) binL[t] = bins[b * 128 + t];
    __syncthreads();
    if (t == 0) {
        int c = 0;
        for (int i = 0; i < 128; ++i)
            if ((binL[i] >> 32) != 0ULL) selL[c++] = (int)(~(unsigned)binL[i]);
        nselS = c;
    }
    __syncthreads();
    const int nsel = nselS;

    for (int need = nsel; need < topk; ++need) {
        unsigned long long best = 0ULL;
        for (int i = t; i < N; i += 256) {
            bool taken = false;
            for (int s2 = 0; s2 < need; ++s2)
                if (selL[s2] == i) { taken = true; break; }
            if (!taken) {
                const unsigned long long pk =
                    ((unsigned long long)score_key(scores[(size_t)b * N + i]) << 32)
                    | (unsigned)(~(unsigned)i);
                if (pk > best) best = pk;
            }
        }
        red[t] = best;
        __syncthreads();
        for (int off = 128; off > 0; off >>= 1) {
            if (t < off) { if (red[t + off] > red[t]) red[t] = red[t + off]; }
            __syncthreads();
        }
        if (t == 0) selL[need] = (int)(~(unsigned)red[0]);
        __syncthreads();
    }

    float* o_feat = out;
    float* o_kpts = out + (size_t)B * topk * 256;
    float* o_idx  = out + (size_t)B * topk * 258;
    for (int e = t; e < topk * 64; e += 256) {
        const int j = e >> 6, q4 = e & 63;
        const int n = selL[j];
        *(float4*)&o_feat[((size_t)b * topk + j) * 256 + q4 * 4] =
            *(const float4*)&desc[((size_t)b * N + n) * 256 + q4 * 4];
    }
    for (int j = t; j < topk; j += 256) {
        const int n = selL[j];
        o_kpts[((size_t)b * topk + j) * 2 + 0] = kpts[((size_t)b * N + n) * 2 + 0];
        o_kpts[((size_t)b * topk + j) * 2 + 1] = kpts[((size_t)b * N + n) * 2 + 1];
        o_idx[(size_t)b * topk + j] = (float)n;
    }
}

extern "C" void kernel_launch(void* const* d_in, const int* in_sizes, int n_in,
                              void* d_out, int out_size, void* d_ws, size_t ws_size,
                              hipStream_t stream) {
    const float* kpts = (const float*)d_in[0];
    const float* desc = (const float*)d_in[1];
    const int*   Hp   = (const int*)d_in[2];
    const int*   Wp   = (const int*)d_in[3];
    const int*   tkp  = (const int*)d_in[4];
    const float* W1   = (const float*)d_in[5];
    const float* b1   = (const float*)d_in[6];
    const float* g1   = (const float*)d_in[7];
    const float* be1  = (const float*)d_in[8];
    const float* W2   = (const float*)d_in[9];
    const float* b2   = (const float*)d_in[10];
    const float* Ws   = (const float*)d_in[11];
    const float* bs   = (const float*)d_in[12];

    const int total = in_sizes[1] / 256;   // B*N
    const int BT    = out_size / 259;      // B*topk
    const int B     = BT / 128;
    const int N     = total / B;
    const int OUT   = in_sizes[11];

    float* ws_v      = (float*)d_ws;
    float* ws_scores = ws_v + 512;
    size_t off = ((size_t)(512 + total) * 4 + 255) & ~(size_t)255;
    unsigned long long* ws_bins = (unsigned long long*)((char*)d_ws + off);
    size_t off2 = (off + (size_t)B * 128 * 8 + 255) & ~(size_t)255;
    uint4* ws_wfrag = (uint4*)((char*)d_ws + off2);        // 256 KB

    prep_kernel<<<1, 256, 0, stream>>>(W2, b2, Ws, bs, ws_v, OUT);
    prep_w1frag<<<64, 256, 0, stream>>>(W1, ws_wfrag);
    init_bins<<<(B * 128 + 255) / 256, 256, 0, stream>>>(ws_bins, B * 128);
    score_kernel<<<(total + 127) / 128, 256, 0, stream>>>(
        desc, kpts, ws_wfrag, b1, g1, be1, Hp, Wp, ws_v, ws_scores, ws_bins, N, total);
    finalize_kernel<<<B, 256, 0, stream>>>(ws_scores, ws_bins, desc, kpts, tkp,
                                           (float*)d_out, B, N);
}

// Round 13
// 379.733 us; speedup vs baseline: 2.0824x; 2.0590x over previous
//
#include <hip/hip_runtime.h>

typedef short bf16x8 __attribute__((ext_vector_type(8)));
typedef float f32x16 __attribute__((ext_vector_type(16)));

__device__ __forceinline__ unsigned short f2bf(float x) {
    unsigned u = __float_as_uint(x);
    return (unsigned short)((u + 0x7FFFu + ((u >> 16) & 1u)) >> 16);
}
__device__ __forceinline__ unsigned score_key(float s) {
    unsigned u = __float_as_uint(s);
    return (u & 0x80000000u) ? ~u : (u | 0x80000000u);
}
__device__ __forceinline__ float key2float(unsigned k) {
    return (k & 0x80000000u) ? __uint_as_float(k ^ 0x80000000u) : __uint_as_float(~k);
}
// truncate-to-bf16 hi of 8 floats (cheap: 3 ops per 2 floats)
__device__ __forceinline__ bf16x8 hi8(const float4& a, const float4& b) {
    union { unsigned w[4]; bf16x8 v; } H;
    const float f[8] = {a.x, a.y, a.z, a.w, b.x, b.y, b.z, b.w};
#pragma unroll
    for (int q = 0; q < 4; ++q) {
        const unsigned u0 = __float_as_uint(f[2 * q]);
        const unsigned u1 = __float_as_uint(f[2 * q + 1]);
        H.w[q] = (u0 >> 16) | (u1 & 0xFFFF0000u);
    }
    return H.v;
}
__device__ __forceinline__ void async_cp16(const uint4* g, uint4* l) {
    __builtin_amdgcn_global_load_lds(
        (const __attribute__((address_space(1))) unsigned int*)g,
        (__attribute__((address_space(3))) unsigned int*)l, 16, 0, 0);
}

// v[j] = sum_o W2[j,o]*Ws[o]; v[256] = dot(b2,Ws)+bs; v[257] = Delta (refine margin)
__global__ void prep_kernel(const float* __restrict__ W2, const float* __restrict__ b2,
                            const float* __restrict__ Ws, const float* __restrict__ bs,
                            float* __restrict__ v, int OUT) {
    __shared__ float vL[256];
    int j = threadIdx.x;
    float acc = 0.f;
    for (int o = 0; o < OUT; ++o) acc += W2[j * OUT + o] * Ws[o];
    v[j] = acc;
    vL[j] = fabsf(acc);
    __syncthreads();
    if (j == 0) {
        float c = bs[0];
        for (int o = 0; o < OUT; ++o) c += b2[o] * Ws[o];
        v[256] = c;
        float sa = 0.f;
        for (int o = 0; o < 256; ++o) sa += vL[o];
        v[257] = fmaxf(1e-5f, sa * (1.f / 128.f));   // ~100x rms bf16-score-noise
    }
}

// W1 -> bf16-hi fragment pack: uint4 idx = kt*1024 + (nt*2+kc)*64 + lane
// elem j of slot = W1[kt*32 + kc*16 + (lane>>5)*8 + j][nt*32 + (lane&31)]  (RNE)
__global__ void prep_w1fragH(const float* __restrict__ W1, uint4* __restrict__ wf) {
    const int s = blockIdx.x * 256 + threadIdx.x;   // 0..8191
    const int kt = s >> 10;
    const int c = (s >> 6) & 15;
    const int lane = s & 63;
    const int nt = c >> 1, kc = c & 1;
    const int col = nt * 32 + (lane & 31);
    const int k0 = kt * 32 + kc * 16 + (lane >> 5) * 8;
    unsigned pk[4];
#pragma unroll
    for (int q = 0; q < 4; ++q) {
        const float x0 = W1[(size_t)(k0 + 2 * q) * 256 + col];
        const float x1 = W1[(size_t)(k0 + 2 * q + 1) * 256 + col];
        pk[q] = (unsigned)f2bf(x0) | ((unsigned)f2bf(x1) << 16);
    }
    wf[s] = make_uint4(pk[0], pk[1], pk[2], pk[3]);
}

__global__ void init_bins(unsigned long long* __restrict__ bins, int n) {
    int i = blockIdx.x * blockDim.x + threadIdx.x;
    if (i < n) bins[i] = 0ULL;
}

// Approx pass: h~ = desc@W1 (1-pass bf16) + b1; LN; SiLU; s~; gid; per-bin approx argmax.
// R5 structure (best measured): 512 thr = 8 waves (4rg x 2cg); wave = 32 rows x 128 cols.
__global__ __launch_bounds__(512, 4) void score_kernel(
    const float* __restrict__ desc, const float* __restrict__ kpts,
    const uint4* __restrict__ wfragH,
    const float* __restrict__ b1, const float* __restrict__ g1, const float* __restrict__ be1,
    const int* __restrict__ Hp, const int* __restrict__ Wp,
    const float* __restrict__ v,
    float* __restrict__ scores, unsigned char* __restrict__ gid8,
    unsigned long long* __restrict__ bins, int N, int total)
{
    __shared__ uint4 BS[2][1024];          // 32 KB hi-frag dbuf
    __shared__ float b1L[256], g1L[256], beL[256], vL[256];
    __shared__ float sums2[128][4];
    __shared__ float dot2[128][2];

    const int t = threadIdx.x;
    const int lane = t & 63;
    const int w = t >> 6;
    const int rg = w >> 1, cg = w & 1;
    const int c31 = lane & 31;
    const int h = lane >> 5;
    const int R0 = blockIdx.x * 128 + rg * 32;
    const int C0 = cg * 128;

    if (t < 256) { b1L[t] = b1[t]; g1L[t] = g1[t]; beL[t] = be1[t]; vL[t] = v[t]; }

    // stage B[0]
    async_cp16(wfragH + t, &BS[0][t]);
    async_cp16(wfragH + 512 + t, &BS[0][512 + t]);

    // A: lane row = R0 + c31; k-slots of chunk kc: kt*32 + kc*16 + h*8 + {0..7}
    const int rA = min(R0 + c31, total - 1);
    const float* pa = desc + (size_t)rA * 256 + h * 8;
    float4 a0A = *(const float4*)(pa + 0);
    float4 a0B = *(const float4*)(pa + 4);

    __syncthreads();   // drains vmcnt: B[0] staged, params visible

    f32x16 acc[4];
#pragma unroll
    for (int n4 = 0; n4 < 4; ++n4) {
        const float bc = b1L[C0 + n4 * 32 + c31];    // fold b1
#pragma unroll
        for (int r = 0; r < 16; ++r) acc[n4][r] = bc;
    }

    for (int kt = 0; kt < 8; ++kt) {
        const int cur = kt & 1;
        const float* pc = pa + kt * 32 + 16;
        float4 a1A = *(const float4*)(pc + 0);
        float4 a1B = *(const float4*)(pc + 4);
        float4 n0A, n0B;
        if (kt < 7) {
            const float* pn = pa + (kt + 1) * 32;
            n0A = *(const float4*)(pn + 0);
            n0B = *(const float4*)(pn + 4);
            async_cp16(wfragH + (size_t)(kt + 1) * 1024 + t, &BS[cur ^ 1][t]);
            async_cp16(wfragH + (size_t)(kt + 1) * 1024 + 512 + t, &BS[cur ^ 1][512 + t]);
        }
        // kc = 0
        {
            const bf16x8 ah = hi8(a0A, a0B);
            bf16x8 bh[4];
#pragma unroll
            for (int j = 0; j < 4; ++j)
                bh[j] = *(const bf16x8*)&BS[cur][((cg * 4 + j) * 2 + 0) * 64 + lane];
#pragma unroll
            for (int j = 0; j < 4; ++j)
                acc[j] = __builtin_amdgcn_mfma_f32_32x32x16_bf16(ah, bh[j], acc[j], 0, 0, 0);
        }
        // kc = 1
        {
            const bf16x8 ah = hi8(a1A, a1B);
            bf16x8 bh[4];
#pragma unroll
            for (int j = 0; j < 4; ++j)
                bh[j] = *(const bf16x8*)&BS[cur][((cg * 4 + j) * 2 + 1) * 64 + lane];
#pragma unroll
            for (int j = 0; j < 4; ++j)
                acc[j] = __builtin_amdgcn_mfma_f32_32x32x16_bf16(ah, bh[j], acc[j], 0, 0, 0);
        }
        a0A = n0A; a0B = n0B;
        __syncthreads();
    }

    // ---- epilogue (R5-verified). C/D: rowIn32=(reg&3)+8*(reg>>2)+4*h, col=C0+n4*32+c31
    float gE[4], beE[4], vE[4];
#pragma unroll
    for (int n4 = 0; n4 < 4; ++n4) {
        const int c = C0 + n4 * 32 + c31;
        gE[n4] = g1L[c]; beE[n4] = beL[c]; vE[n4] = vL[c];
    }
#pragma unroll
    for (int reg = 0; reg < 16; ++reg) {
        float sx = 0.f, sq = 0.f;
#pragma unroll
        for (int n4 = 0; n4 < 4; ++n4) {
            const float x = acc[n4][reg];
            sx += x; sq = fmaf(x, x, sq);
        }
#pragma unroll
        for (int m = 1; m <= 16; m <<= 1) {
            sx += __shfl_xor(sx, m);
            sq += __shfl_xor(sq, m);
        }
        if (c31 == 0) {
            const int rowB = rg * 32 + (reg & 3) + 8 * (reg >> 2) + 4 * h;
            sums2[rowB][cg * 2 + 0] = sx;
            sums2[rowB][cg * 2 + 1] = sq;
        }
    }
    __syncthreads();
#pragma unroll
    for (int reg = 0; reg < 16; ++reg) {
        const int rowB = rg * 32 + (reg & 3) + 8 * (reg >> 2) + 4 * h;
        const float4 s4 = *(const float4*)&sums2[rowB][0];
        const float mu = (s4.x + s4.z) * (1.f / 256.f);
        const float var = (s4.y + s4.w) * (1.f / 256.f) - mu * mu;
        const float rs = 1.f / sqrtf(var + 1e-5f);
        float dot = 0.f;
#pragma unroll
        for (int n4 = 0; n4 < 4; ++n4) {
            const float hv = (acc[n4][reg] - mu) * rs * gE[n4] + beE[n4];
            const float sg = 1.f / (1.f + __expf(-hv));
            dot = fmaf(vE[n4], hv * sg, dot);
        }
#pragma unroll
        for (int m = 1; m <= 16; m <<= 1) dot += __shfl_xor(dot, m);
        if (c31 == 0) dot2[rowB][cg] = dot;
    }
    __syncthreads();
    if (t < 128) {
        const int row = blockIdx.x * 128 + t;
        if (row < total) {
            const float sc = dot2[t][0] + dot2[t][1] + v[256];
            scores[row] = sc;
            const float Wf = (float)Wp[0];
            const int Hi = Hp[0];
            const float t02 = (float)(0.2 * (double)Hi);
            const float t05 = (float)(0.5 * (double)Hi);
            const float t03 = (float)(0.3 * (double)Hi);
            const float x = kpts[(size_t)row * 2 + 0];
            const float y = kpts[(size_t)row * 2 + 1];
            int g = -1;
            if (y > t05) {
                int bgx = (int)(x / Wf * 16.f); bgx = min(max(bgx, 0), 15);
                int bgy = (int)((y - t05) / t05 * 6.f); bgy = min(max(bgy, 0), 5);
                g = 32 + bgy * 16 + bgx;
            } else if (y > t02) {
                int mgx = (int)(x / Wf * 8.f); mgx = min(max(mgx, 0), 7);
                int mgy = (int)((y - t02) / t03 * 4.f); mgy = min(max(mgy, 0), 3);
                g = mgy * 8 + mgx;
            }
            gid8[row] = (unsigned char)(g < 0 ? 255 : g);
            if (g >= 0) {
                const int bb = row / N;
                const int n = row - bb * N;
                const unsigned long long pk =
                    ((unsigned long long)score_key(sc) << 32) | (unsigned)(~(unsigned)n);
                atomicMax(&bins[bb * 128 + g], pk);
            }
        }
    }
}

// Exact refine: re-score (full fp32 MLP) every point with s~ >= binmax~ - Delta,
// atomicMax into exact bins. Guarantees the exact winner is selected.
__global__ __launch_bounds__(256, 4) void refine_kernel(
    const float* __restrict__ desc, const float* __restrict__ scores,
    const unsigned char* __restrict__ gid8, const unsigned long long* __restrict__ bins,
    unsigned long long* __restrict__ exbins,
    const float* __restrict__ W1, const float* __restrict__ b1,
    const float* __restrict__ g1, const float* __restrict__ be1,
    const float* __restrict__ v, int N, int total)
{
    __shared__ int list[128];
    __shared__ int cnt;
    __shared__ float dL[256];
    __shared__ float red[16];

    const int t = threadIdx.x;
    const int lane = t & 63;
    const int w = t >> 6;
    const int R0 = blockIdx.x * 128;
    if (t == 0) cnt = 0;
    __syncthreads();
    const float Delta = v[257];

    if (t < 128) {
        const int row = R0 + t;
        if (row < total) {
            const unsigned char gv = gid8[row];
            if (gv != 255) {
                const int bb = row / N;
                const unsigned mk = (unsigned)(bins[bb * 128 + gv] >> 32);
                if (scores[row] >= key2float(mk) - Delta) {
                    const int p = atomicAdd(&cnt, 1);
                    list[p] = row;
                }
            }
        }
    }
    __syncthreads();
    const int nq = cnt;

    for (int c = 0; c < nq; ++c) {
        const int row = list[c];
        dL[t] = desc[(size_t)row * 256 + t];
        __syncthreads();
        // h_t = b1[t] + sum_k dL[k] * W1[k][t]   (fp32 exact)
        float hj = b1[t];
        const float* wp = W1 + t;
#pragma unroll 8
        for (int k = 0; k < 256; ++k) hj = fmaf(dL[k], wp[(size_t)k * 256], hj);
        // block LN
        float sx = hj, sq = hj * hj;
#pragma unroll
        for (int m = 1; m <= 32; m <<= 1) {
            sx += __shfl_xor(sx, m);
            sq += __shfl_xor(sq, m);
        }
        if (lane == 0) { red[w] = sx; red[8 + w] = sq; }
        __syncthreads();
        const float mu = (red[0] + red[1] + red[2] + red[3]) * (1.f / 256.f);
        const float var = (red[8] + red[9] + red[10] + red[11]) * (1.f / 256.f) - mu * mu;
        const float rs = 1.f / sqrtf(var + 1e-5f);
        const float y = (hj - mu) * rs * g1[t] + be1[t];
        float p = v[t] * (y / (1.f + __expf(-y)));
#pragma unroll
        for (int m = 1; m <= 32; m <<= 1) p += __shfl_xor(p, m);
        if (lane == 0) red[w] = p;
        __syncthreads();
        if (t == 0) {
            const float se = red[0] + red[1] + red[2] + red[3] + v[256];
            const int bb = row / N;
            const int n = row - bb * N;
            const int g = gid8[row];
            const unsigned long long pk =
                ((unsigned long long)score_key(se) << 32) | (unsigned)(~(unsigned)n);
            atomicMax(&exbins[bb * 128 + g], pk);
        }
        __syncthreads();
    }
}

// One block per batch: winners from EXACT bins (bin order), approx fallback, gather.
__global__ __launch_bounds__(256) void finalize_kernel(
    const float* __restrict__ scores, const unsigned long long* __restrict__ exbins,
    const float* __restrict__ desc, const float* __restrict__ kpts,
    const int* __restrict__ tkp, float* __restrict__ out, int B, int N)
{
    const int b = blockIdx.x, t = threadIdx.x;
    const int topk = tkp[0];
    __shared__ int selL[512];
    __shared__ int nselS;
    __shared__ unsigned long long red[256];
    __shared__ unsigned long long binL[128];

    if (t < 128) binL[t] = exbins[b * 128 + t];
    __syncthreads();
    if (t == 0) {
        int c = 0;
        for (int i = 0; i < 128; ++i)
            if ((binL[i] >> 32) != 0ULL) selL[c++] = (int)(~(unsigned)binL[i]);
        nselS = c;
    }
    __syncthreads();
    const int nsel = nselS;

    for (int need = nsel; need < topk; ++need) {   // never runs for this data
        unsigned long long best = 0ULL;
        for (int i = t; i < N; i += 256) {
            bool taken = false;
            for (int s2 = 0; s2 < need; ++s2)
                if (selL[s2] == i) { taken = true; break; }
            if (!taken) {
                const unsigned long long pk =
                    ((unsigned long long)score_key(scores[(size_t)b * N + i]) << 32)
                    | (unsigned)(~(unsigned)i);
                if (pk > best) best = pk;
            }
        }
        red[t] = best;
        __syncthreads();
        for (int off = 128; off > 0; off >>= 1) {
            if (t < off) { if (red[t + off] > red[t]) red[t] = red[t + off]; }
            __syncthreads();
        }
        if (t == 0) selL[need] = (int)(~(unsigned)red[0]);
        __syncthreads();
    }

    float* o_feat = out;
    float* o_kpts = out + (size_t)B * topk * 256;
    float* o_idx  = out + (size_t)B * topk * 258;
    for (int e = t; e < topk * 64; e += 256) {
        const int j = e >> 6, q4 = e & 63;
        const int n = selL[j];
        *(float4*)&o_feat[((size_t)b * topk + j) * 256 + q4 * 4] =
            *(const float4*)&desc[((size_t)b * N + n) * 256 + q4 * 4];
    }
    for (int j = t; j < topk; j += 256) {
        const int n = selL[j];
        o_kpts[((size_t)b * topk + j) * 2 + 0] = kpts[((size_t)b * N + n) * 2 + 0];
        o_kpts[((size_t)b * topk + j) * 2 + 1] = kpts[((size_t)b * N + n) * 2 + 1];
        o_idx[(size_t)b * topk + j] = (float)n;
    }
}

extern "C" void kernel_launch(void* const* d_in, const int* in_sizes, int n_in,
                              void* d_out, int out_size, void* d_ws, size_t ws_size,
                              hipStream_t stream) {
    const float* kpts = (const float*)d_in[0];
    const float* desc = (const float*)d_in[1];
    const int*   Hp   = (const int*)d_in[2];
    const int*   Wp   = (const int*)d_in[3];
    const int*   tkp  = (const int*)d_in[4];
    const float* W1   = (const float*)d_in[5];
    const float* b1   = (const float*)d_in[6];
    const float* g1   = (const float*)d_in[7];
    const float* be1  = (const float*)d_in[8];
    const float* W2   = (const float*)d_in[9];
    const float* b2   = (const float*)d_in[10];
    const float* Ws   = (const float*)d_in[11];
    const float* bs   = (const float*)d_in[12];

    const int total = in_sizes[1] / 256;   // B*N
    const int BT    = out_size / 259;      // B*topk
    const int B     = BT / 128;            // topk = 128 here
    const int N     = total / B;
    const int OUT   = in_sizes[11];

    // workspace layout
    float* ws_v      = (float*)d_ws;                         // 512 floats
    float* ws_scores = ws_v + 512;                           // total floats
    size_t offg = ((size_t)(512 + total) * 4 + 255) & ~(size_t)255;
    unsigned char* ws_gid8 = (unsigned char*)d_ws + offg;    // total bytes
    size_t offb = (offg + (size_t)total + 255) & ~(size_t)255;
    unsigned long long* ws_bins = (unsigned long long*)((char*)d_ws + offb);
    unsigned long long* ws_exbins = ws_bins + (size_t)B * 128;
    size_t offw = (offb + (size_t)2 * B * 128 * 8 + 255) & ~(size_t)255;
    uint4* ws_wfragH = (uint4*)((char*)d_ws + offw);         // 8192 uint4 = 128 KB

    const int nblk = (total + 127) / 128;

    prep_kernel<<<1, 256, 0, stream>>>(W2, b2, Ws, bs, ws_v, OUT);
    prep_w1fragH<<<32, 256, 0, stream>>>(W1, ws_wfragH);
    init_bins<<<(2 * B * 128 + 255) / 256, 256, 0, stream>>>(ws_bins, 2 * B * 128);
    score_kernel<<<nblk, 512, 0, stream>>>(
        desc, kpts, ws_wfragH, b1, g1, be1, Hp, Wp, ws_v,
        ws_scores, ws_gid8, ws_bins, N, total);
    refine_kernel<<<nblk, 256, 0, stream>>>(
        desc, ws_scores, ws_gid8, ws_bins, ws_exbins, W1, b1, g1, be1, ws_v, N, total);
    finalize_kernel<<<B, 256, 0, stream>>>(ws_scores, ws_exbins, desc, kpts, tkp,
                                           (float*)d_out, B, N);
}